// Round 4
// baseline (498.198 us; speedup 1.0000x reference)
//
#include <hip/hip_runtime.h>

#define Vn    12288
#define En    98304
#define Mrows 98304   // V*B

typedef unsigned short u16;
typedef u16   u16x8  __attribute__((ext_vector_type(8)));
typedef __bf16 bf16x8 __attribute__((ext_vector_type(8)));
typedef float f32x4  __attribute__((ext_vector_type(4)));

struct __align__(8) Edge { int s; float w; };

__device__ __forceinline__ float bf2f(u16 u) {
    union { float f; unsigned int i; } c; c.i = ((unsigned int)u) << 16; return c.f;
}
__device__ __forceinline__ u16 f2bf(float f) {
    union { float f; unsigned int i; } c; c.f = f;
    unsigned int r = c.i + 0x7fffu + ((c.i >> 16) & 1u);  // RNE
    return (u16)(r >> 16);
}
__device__ __forceinline__ void load_lds16(const void* g, void* l) {
    __builtin_amdgcn_global_load_lds(
        (const __attribute__((address_space(1))) void*)g,
        (__attribute__((address_space(3))) void*)l, 16, 0, 0);
}

// ---------- x [B][V][256] f32  ->  xb [V][B*256] bf16 (== flat [m=v*8+b][256]) ----------
__global__ void cvt_k(const float* __restrict__ x, u16* __restrict__ xb) {
    int v = blockIdx.x;
    int t = threadIdx.x;
    int b = t >> 5, i = (t & 31) * 8;
    const float* p = x + ((size_t)b * Vn + v) * 256 + i;
    f32x4 a0 = *(const f32x4*)p;
    f32x4 a1 = *(const f32x4*)(p + 4);
    u16x8 r;
    #pragma unroll
    for (int j = 0; j < 4; ++j) { r[j] = f2bf(a0[j]); r[4 + j] = f2bf(a1[j]); }
    *(u16x8*)(xb + (size_t)v * 2048 + b * 256 + i) = r;
}

// ---------- Wt[o][kk] = bf16(W[kk][o]) ----------
__global__ void wtrans_k(const float* __restrict__ w, u16* __restrict__ wt) {
    int kk = blockIdx.x;      // 0..1023
    int o  = threadIdx.x;     // 0..255
    wt[(size_t)o * 1024 + kk] = f2bf(w[(size_t)kk * 256 + o]);
}

// ---------- CSR build ----------
__global__ void count_k(const int* __restrict__ dst, int* __restrict__ counts) {
    int e = blockIdx.x * 256 + threadIdx.x;   // E = 384*256
    atomicAdd(&counts[dst[e]], 1);
}

__global__ void scan_k(const int* __restrict__ counts, int* __restrict__ row_start,
                       int* __restrict__ cursor) {
    __shared__ int par[1024];
    int t = threadIdx.x;
    int base = t * 12;                        // V = 1024*12
    int s = 0;
    #pragma unroll
    for (int i = 0; i < 12; ++i) s += counts[base + i];
    par[t] = s;
    __syncthreads();
    for (int off = 1; off < 1024; off <<= 1) {
        int v_ = (t >= off) ? par[t - off] : 0;
        __syncthreads();
        par[t] += v_;
        __syncthreads();
    }
    int run = (t == 0) ? 0 : par[t - 1];
    for (int i = 0; i < 12; ++i) {
        row_start[base + i] = run;
        cursor[base + i]    = run;
        run += counts[base + i];
    }
    if (t == 1023) row_start[Vn] = En;        // sentinel
}

__global__ void fill_k(const int* __restrict__ src, const int* __restrict__ dst,
                       const float* __restrict__ ew, int* __restrict__ cursor,
                       Edge* __restrict__ csr) {
    int e = blockIdx.x * 256 + threadIdx.x;
    int d = dst[e];
    int p = atomicAdd(&cursor[d], 1);
    Edge ed; ed.s = src[e]; ed.w = ew[e];
    csr[p] = ed;
}

// ---------- sparse L apply + Chebyshev combine, XCD-sliced by batch ----------
// slice = blockIdx & 7 (== XCD under round-robin dispatch); per-XCD working set 6.1 MB.
// Branch-free 4-wide edge chunks (clamp-padded, w=0) -> 4 gathers in flight.
// PREV: 0 -> out = L y ; 1 -> out = 2 L y - prev   (bf16 node-major [V][2048])
template<int PREV>
__global__ __launch_bounds__(256)
void lmul_k(const u16* __restrict__ yb, const u16* __restrict__ prevb,
            u16* __restrict__ outb, const int* __restrict__ row_start,
            const Edge* __restrict__ csr)
{
    int slice = blockIdx.x & 7;
    int v     = (blockIdx.x >> 3) * 8 + (threadIdx.x >> 5);
    int t     = threadIdx.x & 31;
    int s0    = row_start[v];
    int cnt   = row_start[v + 1] - s0;
    size_t soff = (size_t)slice * 256 + (size_t)t * 8;
    float acc[8] = {0.f,0.f,0.f,0.f,0.f,0.f,0.f,0.f};
    for (int j0 = 0; j0 < cnt; j0 += 4) {
        int ss[4]; float ww[4];
        #pragma unroll
        for (int u = 0; u < 4; ++u) {
            int j = j0 + u;
            bool ok = j < cnt;
            Edge e = csr[s0 + (ok ? j : 0)];
            ss[u] = e.s; ww[u] = ok ? e.w : 0.f;
        }
        u16x8 g[4];
        #pragma unroll
        for (int u = 0; u < 4; ++u)
            g[u] = *(const u16x8*)(yb + (size_t)ss[u] * 2048 + soff);
        #pragma unroll
        for (int u = 0; u < 4; ++u)
            #pragma unroll
            for (int j8 = 0; j8 < 8; ++j8) acc[j8] += ww[u] * bf2f(g[u][j8]);
    }
    u16x8 r;
    if (PREV) {
        u16x8 pu = *(const u16x8*)(prevb + (size_t)v * 2048 + soff);
        #pragma unroll
        for (int j8 = 0; j8 < 8; ++j8) r[j8] = f2bf(2.0f * acc[j8] - bf2f(pu[j8]));
    } else {
        #pragma unroll
        for (int j8 = 0; j8 < 8; ++j8) r[j8] = f2bf(acc[j8]);
    }
    *(u16x8*)(outb + (size_t)v * 2048 + soff) = r;
}

// ---------- GEMM: out[m][o] = sum_{k,i} T_k[m][i] * W[k][i][o] + bias ----------
// BM=128, BN=128, BK=64; 256 threads = 4 waves in 2x2 grid, each wave 64x64.
// band = bid % 768, half = bid / 768 (768 % 8 == 0 -> both halves of a band on same XCD).
// XOR chunk swizzle: LDS slot j of row r holds source chunk j ^ (r&7).
__global__ __launch_bounds__(256)
void gemm_k(const u16* __restrict__ x0, const u16* __restrict__ x1,
            const u16* __restrict__ x2, const u16* __restrict__ x3,
            const u16* __restrict__ wt, const float* __restrict__ bias,
            float* __restrict__ outp, float* __restrict__ sums, float* __restrict__ sumsq)
{
    alignas(16) __shared__ char lds[32768];   // A: 16KB @0, B: 16KB @16384
    int tid  = threadIdx.x;
    int wave = tid >> 6;
    int lane = tid & 63;
    int band = blockIdx.x % 768;
    int half = blockIdx.x / 768;
    int m0   = band * 128;
    int n0   = half * 128;
    int wm   = wave & 1;                      // m-half of wave (0/1)
    int wn   = wave >> 1;                     // n-half of wave (0/1)

    f32x4 acc[4][4];
    #pragma unroll
    for (int a = 0; a < 4; ++a)
        #pragma unroll
        for (int b = 0; b < 4; ++b) acc[a][b] = (f32x4){0.f,0.f,0.f,0.f};

    for (int kt = 0; kt < 16; ++kt) {
        int ks = kt >> 2;
        int k0 = (kt & 3) * 64;
        const u16* Ak = (ks == 0) ? x0 : (ks == 1) ? x1 : (ks == 2) ? x2 : x3;
        // A tile: 128 rows x 64k = 16KB = 1024 chunks; 4 per thread
        #pragma unroll
        for (int r = 0; r < 4; ++r) {
            int g  = (r * 4 + wave) * 64 + lane;
            int ml = g >> 3;
            int c  = (g & 7) ^ (ml & 7);
            load_lds16(Ak + ((size_t)(m0 + ml)) * 256 + k0 + c * 8,
                       lds + (r * 4 + wave) * 1024);
        }
        // B tile: 128 o-rows x 64k = 16KB
        #pragma unroll
        for (int r = 0; r < 4; ++r) {
            int g = (r * 4 + wave) * 64 + lane;
            int o = g >> 3;
            int c = (g & 7) ^ (o & 7);
            load_lds16(wt + (size_t)(n0 + o) * 1024 + kt * 64 + c * 8,
                       lds + 16384 + (r * 4 + wave) * 1024);
        }
        __syncthreads();
        #pragma unroll
        for (int kstep = 0; kstep < 2; ++kstep) {
            int cidx = kstep * 4 + (lane >> 4);
            int row  = lane & 15;
            bf16x8 af[4], bfr[4];
            #pragma unroll
            for (int mt = 0; mt < 4; ++mt) {
                int m16 = wm * 64 + mt * 16 + row;
                af[mt] = *(const bf16x8*)(lds + (size_t)(m16 * 8 + (cidx ^ (m16 & 7))) * 16);
            }
            #pragma unroll
            for (int nt = 0; nt < 4; ++nt) {
                int ol = wn * 64 + nt * 16 + row;
                bfr[nt] = *(const bf16x8*)(lds + 16384 + (size_t)(ol * 8 + (cidx ^ (ol & 7))) * 16);
            }
            #pragma unroll
            for (int mt = 0; mt < 4; ++mt)
                #pragma unroll
                for (int nt = 0; nt < 4; ++nt)
                    acc[mt][nt] = __builtin_amdgcn_mfma_f32_16x16x32_bf16(
                        af[mt], bfr[nt], acc[mt][nt], 0, 0, 0);
        }
        __syncthreads();
    }
    // epilogue: C/D layout col(=o)=lane&15, row(=m)=quad*4+reg. f32 out + fused BN stats.
    int crow = lane & 15, quad = lane >> 4;
    #pragma unroll
    for (int nt = 0; nt < 4; ++nt) {
        int o = n0 + wn * 64 + nt * 16 + crow;
        float bv = bias[o];
        float ps = 0.f, pq = 0.f;
        #pragma unroll
        for (int mt = 0; mt < 4; ++mt) {
            #pragma unroll
            for (int r = 0; r < 4; ++r) {
                int m = m0 + wm * 64 + mt * 16 + quad * 4 + r;
                float val = acc[mt][nt][r] + bv;
                outp[((size_t)((m & 7) * Vn + (m >> 3))) * 256 + o] = val;
                ps += val; pq += val * val;
            }
        }
        ps += __shfl_down(ps, 32, 64);  pq += __shfl_down(pq, 32, 64);
        ps += __shfl_down(ps, 16, 64);  pq += __shfl_down(pq, 16, 64);
        if (quad == 0) { atomicAdd(&sums[o], ps); atomicAdd(&sumsq[o], pq); }
    }
}

__global__ void finalize_k(const float* __restrict__ sums, const float* __restrict__ sumsq,
                           const float* __restrict__ gamma, const float* __restrict__ beta,
                           float* __restrict__ scale, float* __restrict__ shift) {
    int o = threadIdx.x;
    const float invM = 1.0f / (float)Mrows;
    float mean = sums[o] * invM;
    float var  = sumsq[o] * invM - mean * mean;
    float sc   = gamma[o] * rsqrtf(var + 1e-5f);
    scale[o] = sc;
    shift[o] = beta[o] - mean * sc;
}

__global__ void bn_relu_k(float* __restrict__ outp, const float* __restrict__ scale,
                          const float* __restrict__ shift) {
    __shared__ float ssc[256], ssh[256];
    int t = threadIdx.x;
    ssc[t] = scale[t]; ssh[t] = shift[t];
    __syncthreads();
    size_t idx = ((size_t)blockIdx.x * 256 + t) * 8;   // covers 25165824 elems
    int o0 = (int)(idx & 255);
    f32x4 a = *(const f32x4*)(outp + idx);
    f32x4 c = *(const f32x4*)(outp + idx + 4);
    #pragma unroll
    for (int i = 0; i < 4; ++i) {
        a[i] = fmaxf(a[i] * ssc[o0 + i]     + ssh[o0 + i],     0.f);
        c[i] = fmaxf(c[i] * ssc[o0 + 4 + i] + ssh[o0 + 4 + i], 0.f);
    }
    *(f32x4*)(outp + idx)     = a;
    *(f32x4*)(outp + idx + 4) = c;
}

extern "C" void kernel_launch(void* const* d_in, const int* in_sizes, int n_in,
                              void* d_out, int out_size, void* d_ws, size_t ws_size,
                              hipStream_t stream) {
    const float* x     = (const float*)d_in[0];
    const float* ew    = (const float*)d_in[1];
    const float* w     = (const float*)d_in[2];
    const float* bias  = (const float*)d_in[3];
    const float* gamma = (const float*)d_in[4];
    const float* beta  = (const float*)d_in[5];
    const int*   esrc  = (const int*)d_in[6];
    const int*   edst  = (const int*)d_in[7];
    float* outp = (float*)d_out;
    char*  ws   = (char*)d_ws;

    u16*   xb        = (u16*)  (ws + 0);           // 50331648 B each, bf16 [V][2048]
    u16*   x1        = (u16*)  (ws + 50331648);
    u16*   x2        = (u16*)  (ws + 100663296);
    u16*   x3        = (u16*)  (ws + 150994944);
    u16*   wt        = (u16*)  (ws + 201326592);   // 524288 B
    Edge*  csr       = (Edge*) (ws + 201850880);   // 786432 B
    int*   counts    = (int*)  (ws + 202637312);   // 49152 B
    int*   row_start = (int*)  (ws + 202686464);   // 49412 B (V+1)
    int*   cursor    = (int*)  (ws + 202736128);   // 49152 B
    float* sums      = (float*)(ws + 202785280);
    float* sumsq     = (float*)(ws + 202786304);
    float* scale     = (float*)(ws + 202787328);
    float* shift     = (float*)(ws + 202788352);

    hipMemsetAsync(counts, 0, 49152, stream);
    hipMemsetAsync(sums, 0, 2048, stream);         // sums + sumsq (adjacent)

    cvt_k<<<Vn, 256, 0, stream>>>(x, xb);
    wtrans_k<<<1024, 256, 0, stream>>>(w, wt);
    count_k<<<384, 256, 0, stream>>>(edst, counts);
    scan_k<<<1, 1024, 0, stream>>>(counts, row_start, cursor);
    fill_k<<<384, 256, 0, stream>>>(esrc, edst, ew, cursor, csr);

    // T1 = L x ; T2 = 2 L T1 - x ; T3 = 2 L T2 - T1   (all bf16 node-major)
    lmul_k<0><<<Vn, 256, 0, stream>>>(xb, nullptr, x1, row_start, csr);
    lmul_k<1><<<Vn, 256, 0, stream>>>(x1, xb,      x2, row_start, csr);
    lmul_k<1><<<Vn, 256, 0, stream>>>(x2, x1,      x3, row_start, csr);

    gemm_k<<<1536, 256, 0, stream>>>(xb, x1, x2, x3, wt, bias, outp, sums, sumsq);

    finalize_k<<<1, 256, 0, stream>>>(sums, sumsq, gamma, beta, scale, shift);
    bn_relu_k<<<12288, 256, 0, stream>>>(outp, scale, shift);
}

// Round 5
// 480.458 us; speedup vs baseline: 1.0369x; 1.0369x over previous
//
#include <hip/hip_runtime.h>

#define Vn    12288
#define En    98304
#define Mrows 98304   // V*B

typedef unsigned short u16;
typedef u16   u16x8  __attribute__((ext_vector_type(8)));
typedef __bf16 bf16x8 __attribute__((ext_vector_type(8)));
typedef float f32x4  __attribute__((ext_vector_type(4)));

struct __align__(8) Edge { int s; float w; };

__device__ __forceinline__ float bf2f(u16 u) {
    union { float f; unsigned int i; } c; c.i = ((unsigned int)u) << 16; return c.f;
}
__device__ __forceinline__ u16 f2bf(float f) {
    union { float f; unsigned int i; } c; c.f = f;
    unsigned int r = c.i + 0x7fffu + ((c.i >> 16) & 1u);  // RNE
    return (u16)(r >> 16);
}
__device__ __forceinline__ void load_lds16(const void* g, void* l) {
    __builtin_amdgcn_global_load_lds(
        (const __attribute__((address_space(1))) void*)g,
        (__attribute__((address_space(3))) void*)l, 16, 0, 0);
}

// ---------- x [B][V][256] f32  ->  xb [V][B*256] bf16 (== flat [m=v*8+b][256]) ----------
__global__ void cvt_k(const float* __restrict__ x, u16* __restrict__ xb) {
    int v = blockIdx.x;
    int t = threadIdx.x;
    int b = t >> 5, i = (t & 31) * 8;
    const float* p = x + ((size_t)b * Vn + v) * 256 + i;
    f32x4 a0 = *(const f32x4*)p;
    f32x4 a1 = *(const f32x4*)(p + 4);
    u16x8 r;
    #pragma unroll
    for (int j = 0; j < 4; ++j) { r[j] = f2bf(a0[j]); r[4 + j] = f2bf(a1[j]); }
    *(u16x8*)(xb + (size_t)v * 2048 + b * 256 + i) = r;
}

// ---------- Wt[o][kk] = bf16(W[kk][o]) ----------
__global__ void wtrans_k(const float* __restrict__ w, u16* __restrict__ wt) {
    int kk = blockIdx.x;      // 0..1023
    int o  = threadIdx.x;     // 0..255
    wt[(size_t)o * 1024 + kk] = f2bf(w[(size_t)kk * 256 + o]);
}

// ---------- CSR build ----------
__global__ void count_k(const int* __restrict__ dst, int* __restrict__ counts) {
    int e = blockIdx.x * 256 + threadIdx.x;   // E = 384*256
    atomicAdd(&counts[dst[e]], 1);
}

__global__ void scan_k(const int* __restrict__ counts, int* __restrict__ row_start,
                       int* __restrict__ cursor) {
    __shared__ int par[1024];
    int t = threadIdx.x;
    int base = t * 12;                        // V = 1024*12
    int s = 0;
    #pragma unroll
    for (int i = 0; i < 12; ++i) s += counts[base + i];
    par[t] = s;
    __syncthreads();
    for (int off = 1; off < 1024; off <<= 1) {
        int v_ = (t >= off) ? par[t - off] : 0;
        __syncthreads();
        par[t] += v_;
        __syncthreads();
    }
    int run = (t == 0) ? 0 : par[t - 1];
    for (int i = 0; i < 12; ++i) {
        row_start[base + i] = run;
        cursor[base + i]    = run;
        run += counts[base + i];
    }
    if (t == 1023) row_start[Vn] = En;        // sentinel
}

__global__ void fill_k(const int* __restrict__ src, const int* __restrict__ dst,
                       const float* __restrict__ ew, int* __restrict__ cursor,
                       Edge* __restrict__ csr) {
    int e = blockIdx.x * 256 + threadIdx.x;
    int d = dst[e];
    int p = atomicAdd(&cursor[d], 1);
    Edge ed; ed.s = src[e]; ed.w = ew[e];
    csr[p] = ed;
}

// ---------- sparse L apply + Chebyshev combine, XCD-sliced by batch ----------
// slice = blockIdx & 7; per-XCD gather working set 6.1 MB (mostly L2-resident).
// 8-wide branch-free edge chunks (clamp-padded, w=0) -> 8 gathers in flight/thread.
// PREV: 0 -> out = L y ; 1 -> out = 2 L y - prev   (bf16 node-major [V][2048])
template<int PREV>
__global__ __launch_bounds__(256)
void lmul_k(const u16* __restrict__ yb, const u16* __restrict__ prevb,
            u16* __restrict__ outb, const int* __restrict__ row_start,
            const Edge* __restrict__ csr)
{
    int slice = blockIdx.x & 7;
    int v     = (blockIdx.x >> 3) * 8 + (threadIdx.x >> 5);
    int t     = threadIdx.x & 31;
    int s0    = row_start[v];
    int cnt   = row_start[v + 1] - s0;
    size_t soff = (size_t)slice * 256 + (size_t)t * 8;
    float acc[8] = {0.f,0.f,0.f,0.f,0.f,0.f,0.f,0.f};
    for (int j0 = 0; j0 < cnt; j0 += 8) {
        int ss[8]; float ww[8];
        #pragma unroll
        for (int u = 0; u < 8; ++u) {
            int j = j0 + u;
            bool ok = j < cnt;
            Edge e = csr[s0 + (ok ? j : 0)];
            ss[u] = e.s; ww[u] = ok ? e.w : 0.f;
        }
        u16x8 g[8];
        #pragma unroll
        for (int u = 0; u < 8; ++u)
            g[u] = *(const u16x8*)(yb + (size_t)ss[u] * 2048 + soff);
        #pragma unroll
        for (int u = 0; u < 8; ++u)
            #pragma unroll
            for (int j8 = 0; j8 < 8; ++j8) acc[j8] += ww[u] * bf2f(g[u][j8]);
    }
    u16x8 r;
    if (PREV) {
        u16x8 pu = *(const u16x8*)(prevb + (size_t)v * 2048 + soff);
        #pragma unroll
        for (int j8 = 0; j8 < 8; ++j8) r[j8] = f2bf(2.0f * acc[j8] - bf2f(pu[j8]));
    } else {
        #pragma unroll
        for (int j8 = 0; j8 < 8; ++j8) r[j8] = f2bf(acc[j8]);
    }
    *(u16x8*)(outb + (size_t)v * 2048 + soff) = r;
}

// ---------- GEMM: out[m][o] = sum_{k,i} T_k[m][i] * W[k][i][o] + bias ----------
// BM=128, BN=256 (full width -> A read exactly once), BK=64.
// 512 threads = 8 waves in 2(m) x 4(n); each wave 64x64 via 4x4 of 16x16x32 MFMA.
// XOR chunk swizzle: LDS slot j of row r holds source chunk j ^ (r&7).
__global__ __launch_bounds__(512)
void gemm_k(const u16* __restrict__ x0, const u16* __restrict__ x1,
            const u16* __restrict__ x2, const u16* __restrict__ x3,
            const u16* __restrict__ wt, const float* __restrict__ bias,
            float* __restrict__ outp, float* __restrict__ sums, float* __restrict__ sumsq)
{
    alignas(16) __shared__ char lds[49152];   // A: 16KB @0, B: 32KB @16384
    int tid  = threadIdx.x;
    int wave = tid >> 6;                      // 0..7
    int lane = tid & 63;
    int m0   = blockIdx.x * 128;
    int wm   = wave & 1;                      // m-half (0/1)
    int wn   = wave >> 1;                     // n-quarter (0..3)

    f32x4 acc[4][4];
    #pragma unroll
    for (int a = 0; a < 4; ++a)
        #pragma unroll
        for (int b = 0; b < 4; ++b) acc[a][b] = (f32x4){0.f,0.f,0.f,0.f};

    for (int kt = 0; kt < 16; ++kt) {
        int ks = kt >> 2;
        int k0 = (kt & 3) * 64;
        const u16* Ak = (ks == 0) ? x0 : (ks == 1) ? x1 : (ks == 2) ? x2 : x3;
        // A tile: 128 rows x 64k = 16KB = 1024 chunks; 2 per thread
        #pragma unroll
        for (int r = 0; r < 2; ++r) {
            int g  = r * 512 + tid;
            int ml = g >> 3;
            int c  = (g & 7) ^ (ml & 7);
            load_lds16(Ak + ((size_t)(m0 + ml)) * 256 + k0 + c * 8,
                       lds + r * 8192 + wave * 1024);
        }
        // B tile: 256 o-rows x 64k = 32KB = 2048 chunks; 4 per thread
        #pragma unroll
        for (int r = 0; r < 4; ++r) {
            int g = r * 512 + tid;
            int o = g >> 3;
            int c = (g & 7) ^ (o & 7);
            load_lds16(wt + (size_t)o * 1024 + kt * 64 + c * 8,
                       lds + 16384 + r * 8192 + wave * 1024);
        }
        __syncthreads();
        #pragma unroll
        for (int kstep = 0; kstep < 2; ++kstep) {
            int cidx = kstep * 4 + (lane >> 4);
            int row  = lane & 15;
            bf16x8 af[4], bfr[4];
            #pragma unroll
            for (int mt = 0; mt < 4; ++mt) {
                int m16 = wm * 64 + mt * 16 + row;
                af[mt] = *(const bf16x8*)(lds + (size_t)(m16 * 8 + (cidx ^ (m16 & 7))) * 16);
            }
            #pragma unroll
            for (int nt = 0; nt < 4; ++nt) {
                int ol = wn * 64 + nt * 16 + row;
                bfr[nt] = *(const bf16x8*)(lds + 16384 + (size_t)(ol * 8 + (cidx ^ (ol & 7))) * 16);
            }
            #pragma unroll
            for (int mt = 0; mt < 4; ++mt)
                #pragma unroll
                for (int nt = 0; nt < 4; ++nt)
                    acc[mt][nt] = __builtin_amdgcn_mfma_f32_16x16x32_bf16(
                        af[mt], bfr[nt], acc[mt][nt], 0, 0, 0);
        }
        __syncthreads();
    }
    // epilogue: C/D layout col(=o)=lane&15, row(=m)=quad*4+reg. f32 out + fused BN stats.
    int crow = lane & 15, quad = lane >> 4;
    #pragma unroll
    for (int nt = 0; nt < 4; ++nt) {
        int o = wn * 64 + nt * 16 + crow;
        float bv = bias[o];
        float ps = 0.f, pq = 0.f;
        #pragma unroll
        for (int mt = 0; mt < 4; ++mt) {
            #pragma unroll
            for (int r = 0; r < 4; ++r) {
                int m = m0 + wm * 64 + mt * 16 + quad * 4 + r;
                float val = acc[mt][nt][r] + bv;
                outp[((size_t)((m & 7) * Vn + (m >> 3))) * 256 + o] = val;
                ps += val; pq += val * val;
            }
        }
        ps += __shfl_down(ps, 32, 64);  pq += __shfl_down(pq, 32, 64);
        ps += __shfl_down(ps, 16, 64);  pq += __shfl_down(pq, 16, 64);
        if (quad == 0) { atomicAdd(&sums[o], ps); atomicAdd(&sumsq[o], pq); }
    }
}

__global__ void finalize_k(const float* __restrict__ sums, const float* __restrict__ sumsq,
                           const float* __restrict__ gamma, const float* __restrict__ beta,
                           float* __restrict__ scale, float* __restrict__ shift) {
    int o = threadIdx.x;
    const float invM = 1.0f / (float)Mrows;
    float mean = sums[o] * invM;
    float var  = sumsq[o] * invM - mean * mean;
    float sc   = gamma[o] * rsqrtf(var + 1e-5f);
    scale[o] = sc;
    shift[o] = beta[o] - mean * sc;
}

__global__ void bn_relu_k(float* __restrict__ outp, const float* __restrict__ scale,
                          const float* __restrict__ shift) {
    __shared__ float ssc[256], ssh[256];
    int t = threadIdx.x;
    ssc[t] = scale[t]; ssh[t] = shift[t];
    __syncthreads();
    size_t idx = ((size_t)blockIdx.x * 256 + t) * 8;   // covers 25165824 elems
    int o0 = (int)(idx & 255);
    f32x4 a = *(const f32x4*)(outp + idx);
    f32x4 c = *(const f32x4*)(outp + idx + 4);
    #pragma unroll
    for (int i = 0; i < 4; ++i) {
        a[i] = fmaxf(a[i] * ssc[o0 + i]     + ssh[o0 + i],     0.f);
        c[i] = fmaxf(c[i] * ssc[o0 + 4 + i] + ssh[o0 + 4 + i], 0.f);
    }
    *(f32x4*)(outp + idx)     = a;
    *(f32x4*)(outp + idx + 4) = c;
}

extern "C" void kernel_launch(void* const* d_in, const int* in_sizes, int n_in,
                              void* d_out, int out_size, void* d_ws, size_t ws_size,
                              hipStream_t stream) {
    const float* x     = (const float*)d_in[0];
    const float* ew    = (const float*)d_in[1];
    const float* w     = (const float*)d_in[2];
    const float* bias  = (const float*)d_in[3];
    const float* gamma = (const float*)d_in[4];
    const float* beta  = (const float*)d_in[5];
    const int*   esrc  = (const int*)d_in[6];
    const int*   edst  = (const int*)d_in[7];
    float* outp = (float*)d_out;
    char*  ws   = (char*)d_ws;

    u16*   xb        = (u16*)  (ws + 0);           // 50331648 B each, bf16 [V][2048]
    u16*   x1        = (u16*)  (ws + 50331648);
    u16*   x2        = (u16*)  (ws + 100663296);
    u16*   x3        = (u16*)  (ws + 150994944);
    u16*   wt        = (u16*)  (ws + 201326592);   // 524288 B
    Edge*  csr       = (Edge*) (ws + 201850880);   // 786432 B
    int*   counts    = (int*)  (ws + 202637312);   // 49152 B
    int*   row_start = (int*)  (ws + 202686464);   // 49412 B (V+1)
    int*   cursor    = (int*)  (ws + 202736128);   // 49152 B
    float* sums      = (float*)(ws + 202785280);
    float* sumsq     = (float*)(ws + 202786304);
    float* scale     = (float*)(ws + 202787328);
    float* shift     = (float*)(ws + 202788352);

    hipMemsetAsync(counts, 0, 49152, stream);
    hipMemsetAsync(sums, 0, 2048, stream);         // sums + sumsq (adjacent)

    cvt_k<<<Vn, 256, 0, stream>>>(x, xb);
    wtrans_k<<<1024, 256, 0, stream>>>(w, wt);
    count_k<<<384, 256, 0, stream>>>(edst, counts);
    scan_k<<<1, 1024, 0, stream>>>(counts, row_start, cursor);
    fill_k<<<384, 256, 0, stream>>>(esrc, edst, ew, cursor, csr);

    // T1 = L x ; T2 = 2 L T1 - x ; T3 = 2 L T2 - T1   (all bf16 node-major)
    lmul_k<0><<<Vn, 256, 0, stream>>>(xb, nullptr, x1, row_start, csr);
    lmul_k<1><<<Vn, 256, 0, stream>>>(x1, xb,      x2, row_start, csr);
    lmul_k<1><<<Vn, 256, 0, stream>>>(x2, x1,      x3, row_start, csr);

    gemm_k<<<Mrows / 128, 512, 0, stream>>>(xb, x1, x2, x3, wt, bias, outp, sums, sumsq);

    finalize_k<<<1, 256, 0, stream>>>(sums, sumsq, gamma, beta, scale, shift);
    bn_relu_k<<<12288, 256, 0, stream>>>(outp, scale, shift);
}